// Round 1
// baseline (140.177 us; speedup 1.0000x reference)
//
#include <hip/hip_runtime.h>
#include <stdint.h>

#define B_ROWS 4096
#define C_OUT  2048
#define C_IN   2048
#define EPS    1e-5f

typedef __attribute__((ext_vector_type(8))) short bf16x8;  // 8 bf16 = 4 VGPRs
typedef __attribute__((ext_vector_type(4))) float f32x4;

// RNE f32 -> bf16
__device__ __forceinline__ unsigned short f2bf(float f) {
    uint32_t u = __float_as_uint(f);
    uint32_t r = (u + 0x7fffu + ((u >> 16) & 1u)) >> 16;
    return (unsigned short)r;
}

// One launch converts both x and w (f32 -> bf16, float4-granular)
__global__ void cvt_f32_bf16_kernel(const float* __restrict__ x,
                                    const float* __restrict__ w,
                                    unsigned short* __restrict__ xb,
                                    unsigned short* __restrict__ wb,
                                    int nx4, int nw4) {
    int i = blockIdx.x * blockDim.x + threadIdx.x;
    const float* src;
    unsigned short* dst;
    if (i < nx4) {
        src = x; dst = xb;
    } else {
        i -= nx4;
        if (i >= nw4) return;
        src = w; dst = wb;
    }
    float4 v = ((const float4*)src)[i];
    ushort4 o;
    o.x = f2bf(v.x); o.y = f2bf(v.y); o.z = f2bf(v.z); o.w = f2bf(v.w);
    ((ushort4*)dst)[i] = o;
}

// R7: counted-vmcnt phase-pipelined GEMM (T3+T4+T5 port of the 8-phase template
// to this shape) + fused GroupNorm + hardtanh.
//   BM=256 x BN=128, BK=64, grid (16,16)=256 blocks = exactly 1/CU.
//   8 waves = 4(M) x 2(N); per-wave 64x64 output -> wave's 64 cols = one GN
//   group (no cross-wave stats, no split-K combine, all 8 waves run epilogue).
//   LDS: TRIPLE buffer, 3 x 48 KB (A 32K + B 16K) = 144 KB, 1 block/CU.
//   Staging: 6 global_load_lds(16B)/K-tile, 2 tiles in flight; steady-state
//   wait is s_waitcnt vmcnt(6) once per K-tile (never 0 until tail). No
//   __syncthreads in the loop - raw s_barrier + counted asm waits.
//   Per K-tile: 2 phases (kk=0/1), each {8 ds_read_b128 + 3 stage issues,
//   s_barrier, lgkmcnt(0)+sched_barrier(0), setprio(1), 16 MFMA, setprio(0),
//   s_barrier}. Swizzle (verified 0-conflict): row of 64 bf16 = 8 granules of
//   16B, granule q stored at q^(row&7); staging pre-swizzles the GLOBAL source
//   so LDS dest stays linear (global_load_lds requirement).
__global__ __launch_bounds__(512, 2)
void gemm_gn_kernel(const unsigned short* __restrict__ A,  // [4096][2048] bf16
                    const unsigned short* __restrict__ W,  // [2048][2048] bf16
                    const float* __restrict__ bias,
                    const float* __restrict__ gnw,
                    const float* __restrict__ gnb,
                    float* __restrict__ out) {
    // buffer b at smem + b*24576: A tile (16384 shorts) then B tile (8192)
    __shared__ __align__(16) unsigned short smem[3 * 24576];  // 144 KB

    const int bc   = blockIdx.x;      // 0..15 col block (128 cols)
    const int br   = blockIdx.y;      // 0..15 row block (256 rows)
    const int tid  = threadIdx.x;     // 0..511
    const int lane = tid & 63;
    const int wave = tid >> 6;        // 0..7
    const int wr   = wave >> 1;       // 0..3 row quarter (64 rows)
    const int wc   = wave & 1;        // 0..1 col half (64 cols = 1 group)
    const int c16  = lane & 15;
    const int quad = lane >> 4;

    f32x4 acc[4][4];
#pragma unroll
    for (int i = 0; i < 4; i++)
#pragma unroll
        for (int j = 0; j < 4; j++) acc[i][j] = (f32x4){0.f, 0.f, 0.f, 0.f};

    // ---- staging addresses ----
    // issue (granule G = tid): row = n*64 + (tid>>3), phys granule tid&7,
    // global granule (tid&7)^(row&7) -> pre-swizzled global source, linear LDS.
    const int r0 = tid >> 3;                        // 0..63
    const int qo = ((tid & 7) ^ (r0 & 7)) * 8;      // element offset in row
    const unsigned short* gA = A + (size_t)(br * 256 + r0) * C_IN + qo;
    const unsigned short* gB = W + (size_t)(bc * 128 + r0) * C_IN + qo;
    const int t8 = tid * 8;

    // half 0: A rows 0..127 (2 issues) + B rows 0..63 (1 issue) = 3 loads
    // half 1: A rows 128..255 + B rows 64..127 = 3 loads
#define STAGE_H(dst, k0, half)                                                                      \
    do {                                                                                            \
        _Pragma("unroll")                                                                           \
        for (int n = (half) * 2; n < (half) * 2 + 2; n++)                                           \
            __builtin_amdgcn_global_load_lds(                                                       \
                (const __attribute__((address_space(1))) void*)(gA + (size_t)(n * 64) * C_IN + (k0)), \
                (__attribute__((address_space(3))) void*)((dst) + n * 4096 + t8), 16, 0, 0);        \
        __builtin_amdgcn_global_load_lds(                                                           \
            (const __attribute__((address_space(1))) void*)(gB + (size_t)((half) * 64) * C_IN + (k0)), \
            (__attribute__((address_space(3))) void*)((dst) + 16384 + (half) * 4096 + t8), 16, 0, 0); \
    } while (0)

    unsigned short* bf0 = smem;
    unsigned short* bf1 = smem + 24576;
    unsigned short* bf2 = smem + 49152;

    // prologue: tiles 0 and 1 in flight (12 loads), wait tile0's 6 only
    STAGE_H(bf0, 0, 0);  STAGE_H(bf0, 0, 1);
    STAGE_H(bf1, 64, 0); STAGE_H(bf1, 64, 1);
    asm volatile("s_waitcnt vmcnt(6)" ::: "memory");
    __builtin_amdgcn_s_barrier();

    const unsigned short* pr = bf0;   // read:  tile kt
    const unsigned short* pn = bf1;   // ready: tile kt+1
    unsigned short*       ps = bf2;   // stage: tile kt+2

#pragma unroll 1
    for (int kt = 0; kt < 32; ++kt) {
        const int k2 = (kt + 2) * 64;
        bf16x8 a[4], bq[4];

        // ---------- phase 0: kk = 0 ----------
        {
            const int qs = (quad ^ (c16 & 7)) * 8;
#pragma unroll
            for (int i = 0; i < 4; i++)
                a[i] = *(const bf16x8*)(pr + (wr * 64 + i * 16 + c16) * 64 + qs);
#pragma unroll
            for (int j = 0; j < 4; j++)
                bq[j] = *(const bf16x8*)(pr + 16384 + (wc * 64 + j * 16 + c16) * 64 + qs);
        }
        if (kt < 30) STAGE_H(ps, k2, 0);
        __builtin_amdgcn_s_barrier();
        asm volatile("s_waitcnt lgkmcnt(0)" ::: "memory");
        __builtin_amdgcn_sched_barrier(0);
        __builtin_amdgcn_s_setprio(1);
#pragma unroll
        for (int i = 0; i < 4; i++)
#pragma unroll
            for (int j = 0; j < 4; j++)
                acc[i][j] = __builtin_amdgcn_mfma_f32_16x16x32_bf16(a[i], bq[j], acc[i][j], 0, 0, 0);
        __builtin_amdgcn_s_setprio(0);
        __builtin_amdgcn_s_barrier();

        // ---------- phase 1: kk = 1 ----------
        {
            const int qs = ((4 + quad) ^ (c16 & 7)) * 8;
#pragma unroll
            for (int i = 0; i < 4; i++)
                a[i] = *(const bf16x8*)(pr + (wr * 64 + i * 16 + c16) * 64 + qs);
#pragma unroll
            for (int j = 0; j < 4; j++)
                bq[j] = *(const bf16x8*)(pr + 16384 + (wc * 64 + j * 16 + c16) * 64 + qs);
        }
        if (kt < 30) STAGE_H(ps, k2, 1);
        __builtin_amdgcn_s_barrier();
        asm volatile("s_waitcnt lgkmcnt(0)" ::: "memory");
        __builtin_amdgcn_sched_barrier(0);
        __builtin_amdgcn_s_setprio(1);
#pragma unroll
        for (int i = 0; i < 4; i++)
#pragma unroll
            for (int j = 0; j < 4; j++)
                acc[i][j] = __builtin_amdgcn_mfma_f32_16x16x32_bf16(a[i], bq[j], acc[i][j], 0, 0, 0);
        __builtin_amdgcn_s_setprio(0);

        // end-of-tile wait: tile kt+1's 6 loads done; tile kt+2's 6 stay in flight
        if (kt < 30)       asm volatile("s_waitcnt vmcnt(6)" ::: "memory");
        else if (kt == 30) asm volatile("s_waitcnt vmcnt(0)" ::: "memory");
        __builtin_amdgcn_s_barrier();

        // rotate triple buffer
        const unsigned short* tmp = pr;
        pr = pn;
        pn = ps;
        ps = (unsigned short*)tmp;
    }

    // ---- epilogue: bias + GroupNorm + hardtanh (all 8 waves, no LDS) ----
    // acc[i][j][r]: row = br*256 + wr*64 + i*16 + quad*4 + r,
    //               col = bc*128 + wc*64 + j*16 + c16. Wave's 64 cols = 1 group.
    const int colbase = bc * 128 + wc * 64;
    const int rowbase = br * 256 + wr * 64;
    float bv[4], gw[4], gb[4];
#pragma unroll
    for (int j = 0; j < 4; j++) {
        int col = colbase + j * 16 + c16;
        bv[j] = bias[col];
        gw[j] = gnw[col];
        gb[j] = gnb[col];
    }
#pragma unroll
    for (int i = 0; i < 4; i++) {
#pragma unroll
        for (int r = 0; r < 4; r++) {
            float s = 0.f, ss = 0.f;
#pragma unroll
            for (int j = 0; j < 4; j++) {
                float v = acc[i][j][r] + bv[j];
                acc[i][j][r] = v;
                s += v;
                ss += v * v;
            }
#pragma unroll
            for (int m = 1; m < 16; m <<= 1) {
                s  += __shfl_xor(s, m, 64);
                ss += __shfl_xor(ss, m, 64);
            }
            float mean = s * (1.f / 64.f);
            float var  = ss * (1.f / 64.f) - mean * mean;
            float rstd = rsqrtf(var + EPS);
            int row = rowbase + i * 16 + quad * 4 + r;
            float* orow = out + (size_t)row * C_OUT;
#pragma unroll
            for (int j = 0; j < 4; j++) {
                float v = (acc[i][j][r] - mean) * rstd * gw[j] + gb[j];
                v = fminf(1.f, fmaxf(-1.f, v));
                orow[colbase + j * 16 + c16] = v;
            }
        }
    }
}

extern "C" void kernel_launch(void* const* d_in, const int* in_sizes, int n_in,
                              void* d_out, int out_size, void* d_ws, size_t ws_size,
                              hipStream_t stream) {
    const float* x    = (const float*)d_in[0];   // [4096, 2048]
    const float* w    = (const float*)d_in[1];   // [2048, 2048]
    const float* bias = (const float*)d_in[2];   // [2048]
    const float* gnw  = (const float*)d_in[3];   // [2048]
    const float* gnb  = (const float*)d_in[4];   // [2048]
    float* out = (float*)d_out;

    unsigned short* xb = (unsigned short*)d_ws;                        // 16 MB
    unsigned short* wb = xb + (size_t)B_ROWS * C_IN;                   //  8 MB

    const int nx4 = B_ROWS * C_IN / 4;   // 2097152
    const int nw4 = C_OUT * C_IN / 4;    // 1048576
    cvt_f32_bf16_kernel<<<(nx4 + nw4 + 255) / 256, 256, 0, stream>>>(x, w, xb, wb, nx4, nw4);

    dim3 grid(C_OUT / 128, B_ROWS / 256);  // (16, 16) = 256 blocks = exactly 1/CU
    gemm_gn_kernel<<<grid, 512, 0, stream>>>(xb, wb, bias, gnw, gnb, out);
}

// Round 2
// 136.942 us; speedup vs baseline: 1.0236x; 1.0236x over previous
//
#include <hip/hip_runtime.h>
#include <stdint.h>

#define B_ROWS 4096
#define C_OUT  2048
#define C_IN   2048
#define EPS    1e-5f

typedef __attribute__((ext_vector_type(8))) short bf16x8;  // 8 bf16 = 4 VGPRs
typedef __attribute__((ext_vector_type(4))) float f32x4;

// RNE f32 -> bf16
__device__ __forceinline__ unsigned short f2bf(float f) {
    uint32_t u = __float_as_uint(f);
    uint32_t r = (u + 0x7fffu + ((u >> 16) & 1u)) >> 16;
    return (unsigned short)r;
}

// One launch converts both x and w (f32 -> bf16, float4-granular)
__global__ void cvt_f32_bf16_kernel(const float* __restrict__ x,
                                    const float* __restrict__ w,
                                    unsigned short* __restrict__ xb,
                                    unsigned short* __restrict__ wb,
                                    int nx4, int nw4) {
    int i = blockIdx.x * blockDim.x + threadIdx.x;
    const float* src;
    unsigned short* dst;
    if (i < nx4) {
        src = x; dst = xb;
    } else {
        i -= nx4;
        if (i >= nw4) return;
        src = w; dst = wb;
    }
    float4 v = ((const float4*)src)[i];
    ushort4 o;
    o.x = f2bf(v.x); o.y = f2bf(v.y); o.z = f2bf(v.z); o.w = f2bf(v.w);
    ((ushort4*)dst)[i] = o;
}

// R8: R7 skeleton (BM=256 x BN=128, BK=64, 8 waves of 64x64, triple-buffered
// LDS 3x48KB, counted vmcnt, grid 256 = 1 block/CU) + the piece R7 missed:
// DOUBLE-BUFFERED REGISTER FRAGMENTS with counted lgkmcnt(8) (the template's
// read-ahead). Phase p issues the NEXT phase's 8 ds_read_b128, then waits
// lgkmcnt(8) -> only confirms the PREVIOUS phase's reads drained (DS completes
// in-order among DS ops), so the LDS drain of each phase hides under the prior
// phase's 16-MFMA cluster instead of serializing before it (R7's lgkmcnt(0)
// full-drain = the 29% MfmaUtil). Tile-boundary vmcnt(3)+barrier moved to
// phase-1-start so phase 1 can legally read-ahead next tile's kk=0 frags from
// pn. 2 barriers/tile (was 4). sched_barrier(0) after every counted wait
// (rule #18: hipcc hoists register-only MFMA past asm waitcnt otherwise).
// VMEM in-flight ledger (steady kt): enter=[kt+1 h0,h1]=6; ph0 stage +3 -> 9;
// ph1 vmcnt(3) drains kt+1's 6; stage +3 -> kt+2's 6. Edges: kt=30 vmcnt(0),
// kt=31 no read-ahead, lgkmcnt(0) before final MFMA.
__global__ __launch_bounds__(512, 2)
void gemm_gn_kernel(const unsigned short* __restrict__ A,  // [4096][2048] bf16
                    const unsigned short* __restrict__ W,  // [2048][2048] bf16
                    const float* __restrict__ bias,
                    const float* __restrict__ gnw,
                    const float* __restrict__ gnb,
                    float* __restrict__ out) {
    // buffer b at smem + b*24576: A tile (16384 shorts) then B tile (8192)
    __shared__ __align__(16) unsigned short smem[3 * 24576];  // 144 KB

    const int bc   = blockIdx.x;      // 0..15 col block (128 cols)
    const int br   = blockIdx.y;      // 0..15 row block (256 rows)
    const int tid  = threadIdx.x;     // 0..511
    const int lane = tid & 63;
    const int wave = tid >> 6;        // 0..7
    const int wr   = wave >> 1;       // 0..3 row quarter (64 rows)
    const int wc   = wave & 1;        // 0..1 col half (64 cols = 1 group)
    const int c16  = lane & 15;
    const int quad = lane >> 4;

    f32x4 acc[4][4];
#pragma unroll
    for (int i = 0; i < 4; i++)
#pragma unroll
        for (int j = 0; j < 4; j++) acc[i][j] = (f32x4){0.f, 0.f, 0.f, 0.f};

    // ---- staging addresses ----
    // issue (granule G = tid): row = n*64 + (tid>>3), phys granule tid&7,
    // global granule (tid&7)^(row&7) -> pre-swizzled global source, linear LDS.
    const int r0 = tid >> 3;                        // 0..63
    const int qo = ((tid & 7) ^ (r0 & 7)) * 8;      // element offset in row
    const unsigned short* gA = A + (size_t)(br * 256 + r0) * C_IN + qo;
    const unsigned short* gB = W + (size_t)(bc * 128 + r0) * C_IN + qo;
    const int t8 = tid * 8;

    // half 0: A rows 0..127 (2 issues) + B rows 0..63 (1 issue) = 3 loads
    // half 1: A rows 128..255 + B rows 64..127 = 3 loads
#define STAGE_H(dst, k0, half)                                                                      \
    do {                                                                                            \
        _Pragma("unroll")                                                                           \
        for (int n = (half) * 2; n < (half) * 2 + 2; n++)                                           \
            __builtin_amdgcn_global_load_lds(                                                       \
                (const __attribute__((address_space(1))) void*)(gA + (size_t)(n * 64) * C_IN + (k0)), \
                (__attribute__((address_space(3))) void*)((dst) + n * 4096 + t8), 16, 0, 0);        \
        __builtin_amdgcn_global_load_lds(                                                           \
            (const __attribute__((address_space(1))) void*)(gB + (size_t)((half) * 64) * C_IN + (k0)), \
            (__attribute__((address_space(3))) void*)((dst) + 16384 + (half) * 4096 + t8), 16, 0, 0); \
    } while (0)

    unsigned short* bf0 = smem;
    unsigned short* bf1 = smem + 24576;
    unsigned short* bf2 = smem + 49152;

    // fragment addressing: logical granule q at phys q ^ (c16&7)
    const int qs0 = (quad ^ (c16 & 7)) * 8;        // kk=0 frags
    const int qs1 = ((4 + quad) ^ (c16 & 7)) * 8;  // kk=1 frags
    int offA[4], offB[4];
#pragma unroll
    for (int i = 0; i < 4; i++) offA[i] = (wr * 64 + i * 16 + c16) * 64;
#pragma unroll
    for (int j = 0; j < 4; j++) offB[j] = 16384 + (wc * 64 + j * 16 + c16) * 64;

    // prologue: tiles 0 and 1 in flight (12 loads), wait tile0's 6 only
    STAGE_H(bf0, 0, 0);  STAGE_H(bf0, 0, 1);
    STAGE_H(bf1, 64, 0); STAGE_H(bf1, 64, 1);
    asm volatile("s_waitcnt vmcnt(6)" ::: "memory");
    __builtin_amdgcn_s_barrier();

    const unsigned short* pr = bf0;   // read:  tile kt
    const unsigned short* pn = bf1;   // ready: tile kt+1
    unsigned short*       ps = bf2;   // stage: tile kt+2

    bf16x8 a0[4], b0[4], a1[4], b1[4];
    // pre-read tile0 kk=0 frags (8 ds_reads outstanding entering the loop)
#pragma unroll
    for (int i = 0; i < 4; i++) a0[i] = *(const bf16x8*)(pr + offA[i] + qs0);
#pragma unroll
    for (int j = 0; j < 4; j++) b0[j] = *(const bf16x8*)(pr + offB[j] + qs0);

#pragma unroll 1
    for (int kt = 0; kt < 32; ++kt) {
        const int k2 = (kt + 2) * 64;

        // ---------- phase 0: read f1 (kk=1, pr), MFMA f0 ----------
#pragma unroll
        for (int i = 0; i < 4; i++) a1[i] = *(const bf16x8*)(pr + offA[i] + qs1);
#pragma unroll
        for (int j = 0; j < 4; j++) b1[j] = *(const bf16x8*)(pr + offB[j] + qs1);
        if (kt < 30) STAGE_H(ps, k2, 0);
        asm volatile("s_waitcnt lgkmcnt(8)" ::: "memory");  // f0 drained, f1 in flight
        __builtin_amdgcn_sched_barrier(0);
        __builtin_amdgcn_s_setprio(1);
#pragma unroll
        for (int i = 0; i < 4; i++)
#pragma unroll
            for (int j = 0; j < 4; j++)
                acc[i][j] = __builtin_amdgcn_mfma_f32_16x16x32_bf16(a0[i], b0[j], acc[i][j], 0, 0, 0);
        __builtin_amdgcn_s_setprio(0);

        // ---------- phase 1: read next-tile f0 (kk=0, pn), MFMA f1 ----------
        if (kt < 30)       asm volatile("s_waitcnt vmcnt(3)" ::: "memory");  // kt+1 landed
        else if (kt == 30) asm volatile("s_waitcnt vmcnt(0)" ::: "memory");  // tile 31 landed
        if (kt < 31) {
            __builtin_amdgcn_s_barrier();   // all waves confirm pn landed
#pragma unroll
            for (int i = 0; i < 4; i++) a0[i] = *(const bf16x8*)(pn + offA[i] + qs0);
#pragma unroll
            for (int j = 0; j < 4; j++) b0[j] = *(const bf16x8*)(pn + offB[j] + qs0);
            if (kt < 30) STAGE_H(ps, k2, 1);
            asm volatile("s_waitcnt lgkmcnt(8)" ::: "memory");  // f1 drained, f0' in flight
        } else {
            asm volatile("s_waitcnt lgkmcnt(0)" ::: "memory");  // final: drain f1
        }
        __builtin_amdgcn_sched_barrier(0);
        __builtin_amdgcn_s_setprio(1);
#pragma unroll
        for (int i = 0; i < 4; i++)
#pragma unroll
            for (int j = 0; j < 4; j++)
                acc[i][j] = __builtin_amdgcn_mfma_f32_16x16x32_bf16(a1[i], b1[j], acc[i][j], 0, 0, 0);
        __builtin_amdgcn_s_setprio(0);
        // end-of-tile barrier: all waves' f1 reads of pr have COMPLETED
        // (drained at the lgkmcnt above) -> next tile may stage into ps'=pr.
        if (kt < 31) __builtin_amdgcn_s_barrier();

        // rotate triple buffer
        const unsigned short* tmp = pr;
        pr = pn;
        pn = ps;
        ps = (unsigned short*)tmp;
    }

    // ---- epilogue: bias + GroupNorm + hardtanh (all 8 waves, no LDS) ----
    // acc[i][j][r]: row = br*256 + wr*64 + i*16 + quad*4 + r,
    //               col = bc*128 + wc*64 + j*16 + c16. Wave's 64 cols = 1 group.
    const int colbase = bc * 128 + wc * 64;
    const int rowbase = br * 256 + wr * 64;
    float bv[4], gw[4], gb[4];
#pragma unroll
    for (int j = 0; j < 4; j++) {
        int col = colbase + j * 16 + c16;
        bv[j] = bias[col];
        gw[j] = gnw[col];
        gb[j] = gnb[col];
    }
#pragma unroll
    for (int i = 0; i < 4; i++) {
#pragma unroll
        for (int r = 0; r < 4; r++) {
            float s = 0.f, ss = 0.f;
#pragma unroll
            for (int j = 0; j < 4; j++) {
                float v = acc[i][j][r] + bv[j];
                acc[i][j][r] = v;
                s += v;
                ss += v * v;
            }
#pragma unroll
            for (int m = 1; m < 16; m <<= 1) {
                s  += __shfl_xor(s, m, 64);
                ss += __shfl_xor(ss, m, 64);
            }
            float mean = s * (1.f / 64.f);
            float var  = ss * (1.f / 64.f) - mean * mean;
            float rstd = rsqrtf(var + EPS);
            int row = rowbase + i * 16 + quad * 4 + r;
            float* orow = out + (size_t)row * C_OUT;
#pragma unroll
            for (int j = 0; j < 4; j++) {
                float v = (acc[i][j][r] - mean) * rstd * gw[j] + gb[j];
                v = fminf(1.f, fmaxf(-1.f, v));
                orow[colbase + j * 16 + c16] = v;
            }
        }
    }
}

extern "C" void kernel_launch(void* const* d_in, const int* in_sizes, int n_in,
                              void* d_out, int out_size, void* d_ws, size_t ws_size,
                              hipStream_t stream) {
    const float* x    = (const float*)d_in[0];   // [4096, 2048]
    const float* w    = (const float*)d_in[1];   // [2048, 2048]
    const float* bias = (const float*)d_in[2];   // [2048]
    const float* gnw  = (const float*)d_in[3];   // [2048]
    const float* gnb  = (const float*)d_in[4];   // [2048]
    float* out = (float*)d_out;

    unsigned short* xb = (unsigned short*)d_ws;                        // 16 MB
    unsigned short* wb = xb + (size_t)B_ROWS * C_IN;                   //  8 MB

    const int nx4 = B_ROWS * C_IN / 4;   // 2097152
    const int nw4 = C_OUT * C_IN / 4;    // 1048576
    cvt_f32_bf16_kernel<<<(nx4 + nw4 + 255) / 256, 256, 0, stream>>>(x, w, xb, wb, nx4, nw4);

    dim3 grid(C_OUT / 128, B_ROWS / 256);  // (16, 16) = 256 blocks = exactly 1/CU
    gemm_gn_kernel<<<grid, 512, 0, stream>>>(xb, wb, bias, gnw, gnb, out);
}